// Round 10
// baseline (5120.378 us; speedup 1.0000x reference)
//
#include <hip/hip_runtime.h>
#include <hip/hip_bf16.h>

// WeightedGNN forward, MI355X. Round 10: the recurrence is per-b independent ->
// ONE block per b (16 blocks x 1024 thr) runs all 64 iterations with h resident
// in LDS. Zero cross-block traffic, zero barriers, zero per-iter launches
// (R5-R9 showed launch gaps ~15 us/iter and coherent handoffs ~800 GB/s were
// the walls). LDS = 64 KB exactly: h[64][256] XOR-swizzled + 32 KB union
// (Pt transpose halves + LN stats / h' / final-reduce).
// B=16, L=64, D=256, NRELS=8.

#define DD 256
#define LLEN 64
#define BBAT 16
#define NROWS 1024   // B*L

typedef __attribute__((ext_vector_type(8))) short short8;   // 8 bf16 = 4 VGPRs
typedef __attribute__((ext_vector_type(4))) short short4v;  // 4 bf16 = 8 B
typedef __attribute__((ext_vector_type(4))) float f32x4;

__device__ inline unsigned short f2bf(float x) {
    unsigned int u = __float_as_uint(x);
    unsigned int r = (u + 0x7fffu + ((u >> 16) & 1u)) >> 16;
    return (unsigned short)r;
}

// fast tanh: |err| ~1e-6, overflow-safe (threshold is 2.4e-2)
__device__ inline float ftanh(float x) {
    float ax = __builtin_fabsf(x);
    float e = __expf(-2.f * ax);
    float t = __fdividef(1.f - e, 1.f + e);
    return __builtin_copysignf(t, x);
}

// ------- one-time: W_proj [256][2048] fp32 -> bf16 B-fragment layout ----------
__global__ __launch_bounds__(256) void k_cvtW(const float* __restrict__ Wp,
                                              unsigned short* __restrict__ Wf) {
    int t = blockIdx.x * 256 + threadIdx.x;   // 65536
    int l = t & 63; int rest = t >> 6;
    int tk = rest & 7; rest >>= 3;
    int tn = rest & 15; int hh = rest >> 4;
    int kbase = tk * 32 + (l >> 4) * 8;
    int n = hh * 256 + tn * 16 + (l & 15);
    union { short8 v; unsigned short u[8]; } pk;
#pragma unroll
    for (int j = 0; j < 8; ++j) pk.u[j] = f2bf(Wp[(kbase + j) * 2048 + n]);
    *(short8*)(Wf + (long)t * 8) = pk.v;
}

// ------- one-time: A_rels -> bf16 A-fragment layout, K-order k = h*64 + i -----
__global__ __launch_bounds__(256) void k_cvtA(const float* __restrict__ A,
                                              unsigned short* __restrict__ Af) {
    int t = blockIdx.x * 256 + threadIdx.x;   // 65536
    int lane = t & 63;
    int tk = (t >> 6) & 15;
    int jg = (t >> 10) & 3;
    int b  = t >> 12;
    int j = jg * 16 + (lane & 15);
    int kbase = tk * 32 + (lane >> 4) * 8;
    int h  = kbase >> 6;
    int i0 = kbase & 63;
    union { short8 v; unsigned short u[8]; } pk;
#pragma unroll
    for (int jj = 0; jj < 8; ++jj)
        pk.u[jj] = f2bf(A[((long)(b * 64 + i0 + jj) * 64 + j) * 8 + h]);
    *(short8*)(Af + (long)t * 8) = pk.v;
}

// ------- one-time: W_out [256][256] fp32 -> bf16 B-fragment layout ------------
__global__ __launch_bounds__(256) void k_cvtWo(const float* __restrict__ Wo,
                                               unsigned short* __restrict__ Wof) {
    int t = blockIdx.x * 256 + threadIdx.x;   // 8192
    int lane = t & 63;
    int tk = (t >> 6) & 7;
    int nt = t >> 9;
    int kbase = tk * 32 + (lane >> 4) * 8;
    int n = nt * 16 + (lane & 15);
    union { short8 v; unsigned short u[8]; } pk;
#pragma unroll
    for (int j = 0; j < 8; ++j) pk.u[j] = f2bf(Wo[(kbase + j) * 256 + n]);
    *(short8*)(Wof + (long)t * 8) = pk.v;
}

// ---------------- in_proj: gather emb + [1024x256]@[256x768] -----------------
__global__ __launch_bounds__(256) void k_inproj(
    const int* __restrict__ tokens, const float* __restrict__ emb,
    const float* __restrict__ W_in, const float* __restrict__ b_in,
    float* __restrict__ shiftb, float* __restrict__ scaleb, float* __restrict__ projx)
{
    __shared__ float xs[8][DD];
    const int t = threadIdx.x;
    const int row0 = blockIdx.x * 8;
    for (int r = 0; r < 8; ++r) {
        int row = row0 + r;
        int b = row >> 6, l = row & 63;
        int tok = tokens[l * BBAT + b];
        xs[r][t] = emb[(long)tok * DD + t];
    }
    __syncthreads();
    float a0[8], a1[8], a2[8];
#pragma unroll
    for (int r = 0; r < 8; ++r) { a0[r] = a1[r] = a2[r] = 0.f; }
    for (int k = 0; k < DD; ++k) {
        float w0 = W_in[k * 768 + t];
        float w1 = W_in[k * 768 + 256 + t];
        float w2 = W_in[k * 768 + 512 + t];
#pragma unroll
        for (int r = 0; r < 8; ++r) {
            float x = xs[r][k];
            a0[r] = fmaf(x, w0, a0[r]);
            a1[r] = fmaf(x, w1, a1[r]);
            a2[r] = fmaf(x, w2, a2[r]);
        }
    }
    float bi0 = b_in[t], bi1 = b_in[256 + t], bi2 = b_in[512 + t];
#pragma unroll
    for (int r = 0; r < 8; ++r) {
        int row = row0 + r;
        shiftb[row * DD + t] = a0[r] + bi0;
        scaleb[row * DD + t] = a1[r] + bi1;
        projx [row * DD + t] = a2[r] + bi2;
    }
}

// ---------------- persistent per-b block: all 64 iterations ------------------
// 16 blocks x 1024 thr (16 waves). Phase 1 roles: wave (mt=w&3 i-tile, ng=w>>2
// d-group). GEMM-lin/gate/GEMM2 roles: (jt=w&3, dg=w>>2). Per hh (8 chunks of
// K): GEMM-A 16x64 per wave (K=256), in-fragment LN over d, Pt transpose in two
// 32-i halves, GEMM-lin K-tile accumulate into registers. Gate: shrink/LN/gate
// from register lin, h'->hsb, GEMM2, y->hpb (next h) or root-reduce (last).
__global__ __launch_bounds__(1024) void k_loop(
    const int* __restrict__ tokens,
    const unsigned short* __restrict__ Wf,     // [8*16][8][64][8]
    const unsigned short* __restrict__ Af,     // [16][4][16][64][8]
    const unsigned short* __restrict__ Wof,    // [16][8][64][8]
    const float* __restrict__ bp,
    const float* __restrict__ bout,
    const float* __restrict__ projx,
    const float* __restrict__ shiftb,
    const float* __restrict__ scaleb,
    const float* __restrict__ root,
    float* __restrict__ out)
{
    __shared__ __align__(128) char smem[65536];
    unsigned short* hpb = (unsigned short*)smem;               // [64][256] swizzled
    unsigned short* Pt  = (unsigned short*)(smem + 32768);     // [256][40]
    float* pstat   = (float*)(smem + 53248);                   // [64][4][2]
    float* mstat   = (float*)(smem + 55296);                   // [64][2]
    float* linpart = (float*)(smem + 32768);                   // [64][4][2] (alias Pt)
    unsigned short* hsb = (unsigned short*)(smem + 32768);     // [64][256] swz (alias)
    float* yjpart  = (float*)(smem + 32768);                   // [4][256] (alias)

    const int t = threadIdx.x;
    const int w = t >> 6, lane = t & 63;
    const int q = lane >> 4, ln = lane & 15;
    const int b = blockIdx.x;
    const int mt = w & 3, ng = w >> 2;         // phase-1 roles
    const int jt = mt,    dg = ng;             // lin/gate/GEMM2 roles
    const long rowb = (long)b * 64;

    // lengths[b] via ballot (lane = l), every wave redundantly
    const int len = __popcll(__ballot(tokens[lane * BBAT + b] != 0));

    // h := 0
    {
        short8 z = (short8){0,0,0,0,0,0,0,0};
        *(short8*)(hpb + t * 16) = z;
        *(short8*)(hpb + t * 16 + 8) = z;
    }
    __syncthreads();

    for (int it = 0; it < 64; ++it) {
        f32x4 acc2[4];
#pragma unroll
        for (int dl = 0; dl < 4; ++dl) acc2[dl] = (f32x4){0.f, 0.f, 0.f, 0.f};

        // =============== phase 1: per hh chunk ===============
        for (int hh = 0; hh < 8; ++hh) {
            // ---- GEMM-A: rows i=mt*16.., cols d=(ng*4+nl)*16.., K=256 ----
            f32x4 accP[4];
#pragma unroll
            for (int nl = 0; nl < 4; ++nl) accP[nl] = (f32x4){0.f, 0.f, 0.f, 0.f};
            const int arow = mt * 16 + ln;
#pragma unroll
            for (int tk = 0; tk < 8; ++tk) {
                short8 a = *(const short8*)(hpb + arow * 256 + (((tk * 4 + q) ^ (arow & 31)) << 3));
#pragma unroll
                for (int nl = 0; nl < 4; ++nl) {
                    int nt = ng * 4 + nl;
                    short8 bb = *(const short8*)(Wf + ((long)(hh * 16 + nt) * 8 + tk) * 512 + lane * 8);
                    accP[nl] = __builtin_amdgcn_mfma_f32_16x16x32_bf16(a, bb, accP[nl], 0, 0, 0);
                }
            }
            // ---- bias + LN partials (this wave covers 64 d) ----
            float v[4][4];
            float bpv[4];
#pragma unroll
            for (int nl = 0; nl < 4; ++nl) bpv[nl] = bp[hh * 256 + (ng * 4 + nl) * 16 + ln];
#pragma unroll
            for (int r = 0; r < 4; ++r) {
                float s = 0.f, ss = 0.f;
#pragma unroll
                for (int nl = 0; nl < 4; ++nl) {
                    float x = accP[nl][r] + bpv[nl];
                    v[nl][r] = x;
                    s += x; ss += x * x;
                }
#pragma unroll
                for (int msk = 1; msk < 16; msk <<= 1) {
                    s += __shfl_xor(s, msk); ss += __shfl_xor(ss, msk);
                }
                if (ln == 0) {
                    int i = mt * 16 + q * 4 + r;
                    pstat[i * 8 + ng * 2 + 0] = s;
                    pstat[i * 8 + ng * 2 + 1] = ss;
                }
            }
            __syncthreads();
            if (t < 64) {
                float S = 0.f, SS = 0.f;
#pragma unroll
                for (int g = 0; g < 4; ++g) { S += pstat[t * 8 + g * 2]; SS += pstat[t * 8 + g * 2 + 1]; }
                float mean = S * (1.f / 256.f);
                float var  = SS * (1.f / 256.f) - mean * mean;
                mstat[t * 2 + 0] = mean;
                mstat[t * 2 + 1] = rsqrtf(var + 1e-5f);
            }
            __syncthreads();
            float mn[4], rs[4];
#pragma unroll
            for (int r = 0; r < 4; ++r) {
                int i = mt * 16 + q * 4 + r;
                mn[r] = mstat[i * 2]; rs[r] = mstat[i * 2 + 1];
            }
            // ---- two i-halves: transpose -> Pt, GEMM-lin K-tile ----
#pragma unroll
            for (int ih = 0; ih < 2; ++ih) {
                if ((mt >> 1) == ih) {
#pragma unroll
                    for (int nl = 0; nl < 4; ++nl) {
                        int d = (ng * 4 + nl) * 16 + ln;
                        short4v pk;
#pragma unroll
                        for (int r = 0; r < 4; ++r)
                            pk[r] = (short)f2bf((v[nl][r] - mn[r]) * rs[r]);
                        *(short4v*)(Pt + d * 40 + (mt & 1) * 16 + q * 4) = pk;
                    }
                }
                __syncthreads();
                int gtk = hh * 2 + ih;
                short8 aA = *(const short8*)(Af + ((long)(b * 4 + jt) * 16 + gtk) * 512 + lane * 8);
#pragma unroll
                for (int dl = 0; dl < 4; ++dl) {
                    int dt = dg * 4 + dl;
                    short8 bb = *(const short8*)(Pt + (dt * 16 + ln) * 40 + q * 8);
                    acc2[dl] = __builtin_amdgcn_mfma_f32_16x16x32_bf16(aA, bb, acc2[dl], 0, 0, 0);
                }
                __syncthreads();
            }
        }

        // =============== gate: shrink + LN + gate + GEMM2 ===============
        // lin at (j = jt*16+q*4+r, d = (dg*4+dl)*16+ln) in acc2[dl][r]
        float tv[4][4];
#pragma unroll
        for (int dl = 0; dl < 4; ++dl) {
            int d = (dg * 4 + dl) * 16 + ln;
#pragma unroll
            for (int r = 0; r < 4; ++r) {
                int j = jt * 16 + q * 4 + r;
                float lp = acc2[dl][r];
                float shr = lp - ftanh(lp);
                tv[dl][r] = projx[(rowb + j) * 256 + d] + shr;
            }
        }
#pragma unroll
        for (int r = 0; r < 4; ++r) {
            float s = 0.f, ss = 0.f;
#pragma unroll
            for (int dl = 0; dl < 4; ++dl) { s += tv[dl][r]; ss += tv[dl][r] * tv[dl][r]; }
#pragma unroll
            for (int msk = 1; msk < 16; msk <<= 1) {
                s += __shfl_xor(s, msk); ss += __shfl_xor(ss, msk);
            }
            if (ln == 0) {
                int j = jt * 16 + q * 4 + r;
                linpart[j * 8 + dg * 2 + 0] = s;
                linpart[j * 8 + dg * 2 + 1] = ss;
            }
        }
        __syncthreads();
        float mn2[4], rs2[4];
#pragma unroll
        for (int r = 0; r < 4; ++r) {
            int j = jt * 16 + q * 4 + r;
            float S = 0.f, SS = 0.f;
#pragma unroll
            for (int g = 0; g < 4; ++g) { S += linpart[j * 8 + g * 2]; SS += linpart[j * 8 + g * 2 + 1]; }
            float mean = S * (1.f / 256.f);
            float var  = SS * (1.f / 256.f) - mean * mean;
            mn2[r] = mean; rs2[r] = rsqrtf(var + 1e-5f);
        }
        __syncthreads();   // linpart consumed -> hsb may overwrite (alias)
#pragma unroll
        for (int dl = 0; dl < 4; ++dl) {
            int d = (dg * 4 + dl) * 16 + ln;
#pragma unroll
            for (int r = 0; r < 4; ++r) {
                int j = jt * 16 + q * 4 + r;
                float nv = (tv[dl][r] - mn2[r]) * rs2[r];
                float hv = fmaf(shiftb[(rowb + j) * 256 + d], nv, scaleb[(rowb + j) * 256 + d]);
                hsb[j * 256 + (((d >> 3) ^ (j & 31)) << 3) + (d & 7)] = f2bf(fmaxf(hv, 0.f));
            }
        }
        __syncthreads();
        // ---- GEMM2: y = h' @ W_out ----
        f32x4 acc3[4];
#pragma unroll
        for (int dl = 0; dl < 4; ++dl) acc3[dl] = (f32x4){0.f, 0.f, 0.f, 0.f};
        const int hrow = jt * 16 + ln;
#pragma unroll
        for (int tk = 0; tk < 8; ++tk) {
            short8 a = *(const short8*)(hsb + hrow * 256 + (((tk * 4 + q) ^ (hrow & 31)) << 3));
#pragma unroll
            for (int dl = 0; dl < 4; ++dl) {
                int nt2 = dg * 4 + dl;
                short8 wfr = *(const short8*)(Wof + ((long)nt2 * 8 + tk) * 512 + lane * 8);
                acc3[dl] = __builtin_amdgcn_mfma_f32_16x16x32_bf16(a, wfr, acc3[dl], 0, 0, 0);
            }
        }
        const bool maskz = ((64 - it) > len);
        float y[4][4];
#pragma unroll
        for (int dl = 0; dl < 4; ++dl) {
            float bo = bout[(dg * 4 + dl) * 16 + ln];
#pragma unroll
            for (int r = 0; r < 4; ++r)
                y[dl][r] = maskz ? 0.f : ftanh(acc3[dl][r] + bo);
        }

        if (it < 63) {
            // y -> hpb (next h); hpb reads finished in phase 1 (many syncs ago)
#pragma unroll
            for (int dl = 0; dl < 4; ++dl) {
                int d = (dg * 4 + dl) * 16 + ln;
#pragma unroll
                for (int r = 0; r < 4; ++r) {
                    int j = jt * 16 + q * 4 + r;
                    hpb[j * 256 + (((d >> 3) ^ (j & 31)) << 3) + (d & 7)] = f2bf(y[dl][r]);
                }
            }
            __syncthreads();   // h ready; also orders hsb reads vs next-iter aliases
        } else {
            // final: out[b,d] = sum_j y[j,d] * root[b,j]
            float rt4[4];
#pragma unroll
            for (int r = 0; r < 4; ++r) rt4[r] = root[rowb + jt * 16 + q * 4 + r];
            float pd[4];
#pragma unroll
            for (int dl = 0; dl < 4; ++dl) {
                float p = 0.f;
#pragma unroll
                for (int r = 0; r < 4; ++r) p = fmaf(y[dl][r], rt4[r], p);
                p += __shfl_xor(p, 16);
                p += __shfl_xor(p, 32);
                pd[dl] = p;   // sum over q (and r): rows jt*16..+15 done via lanes
            }
            __syncthreads();   // GEMM2 hsb reads done -> yjpart may overwrite (alias)
            if (q == 0) {
#pragma unroll
                for (int dl = 0; dl < 4; ++dl)
                    yjpart[jt * 256 + (dg * 4 + dl) * 16 + ln] = pd[dl];
            }
            __syncthreads();
            if (t < 256) {
                float o = yjpart[t] + yjpart[256 + t] + yjpart[512 + t] + yjpart[768 + t];
                out[b * 256 + t] = o;
            }
        }
    }
}

extern "C" void kernel_launch(void* const* d_in, const int* in_sizes, int n_in,
                              void* d_out, int out_size, void* d_ws, size_t ws_size,
                              hipStream_t stream)
{
    const int*   tokens = (const int*)  d_in[0];
    const float* A      = (const float*)d_in[1];
    const float* root   = (const float*)d_in[2];
    const float* emb    = (const float*)d_in[3];
    const float* Wp     = (const float*)d_in[4];
    const float* bp     = (const float*)d_in[5];
    const float* Wi     = (const float*)d_in[6];
    const float* bi     = (const float*)d_in[7];
    const float* Wo     = (const float*)d_in[8];
    const float* bo     = (const float*)d_in[9];
    float* out = (float*)d_out;

    char* ws = (char*)d_ws;
    float* shiftb  = (float*)ws;
    float* scaleb  = shiftb + NROWS * DD;
    float* projx   = scaleb + NROWS * DD;
    unsigned short* Wf  = (unsigned short*)(projx + NROWS * DD);  // 1 MB
    unsigned short* Af  = Wf + 524288;                            // 1 MB
    unsigned short* Wof = Af + 524288;                            // 128 KB

    k_cvtW<<<256, 256, 0, stream>>>(Wp, Wf);
    k_cvtA<<<256, 256, 0, stream>>>(A, Af);
    k_cvtWo<<<32, 256, 0, stream>>>(Wo, Wof);
    k_inproj<<<128, 256, 0, stream>>>(tokens, emb, Wi, bi, shiftb, scaleb, projx);
    k_loop<<<16, 1024, 0, stream>>>(tokens, Wf, Af, Wof, bp, bo,
                                    projx, shiftb, scaleb, root, out);
}